// Round 4
// baseline (498.302 us; speedup 1.0000x reference)
//
#include <hip/hip_runtime.h>

// Problem constants (setup_inputs is fixed)
#define BATCH 2
#define NTXT  2048
#define TMED  4
#define MMED  256
#define TM    (TMED * MMED)      // 1024 kv rows per batch
#define DIM   1024
#define NH    16
#define DHD   64
#define KVW   2048               // k|v concatenated width
#define RMAX  256                // max real rows per batch supported
#define MCAP  (RMAX * NH)        // 4096 max (i,h) rows per batch

typedef _Float16 f16x8 __attribute__((ext_vector_type(8)));
typedef float    f32x4 __attribute__((ext_vector_type(4)));

// ---------------------------------------------------------------------------
// find positions of the 1st..5th ones in loc[b,:] (wave 0 only), -> posS[5]
// (locations are 0/1; txt_time = cumsum, so pos[k] = first index with tt>=k+1)
// ---------------------------------------------------------------------------
__device__ __forceinline__ void find5(const int* __restrict__ loc, int b,
                                      int* posS, int tid) {
  if (tid < 64) {
    int pos[5] = {NTXT, NTXT, NTXT, NTXT, NTXT};
    int found = 0;
    for (int base = 0; base < NTXT && found < 5; base += 64) {
      unsigned long long m = __ballot(loc[b * NTXT + base + tid] != 0);
      while (m && found < 5) {
        const int p = __ffsll(m) - 1;
        pos[found++] = base + p;
        m &= m - 1;
      }
    }
    if (tid == 0) {
#pragma unroll
      for (int k = 0; k < 5; k++) posS[k] = pos[k];
    }
  }
  __syncthreads();
}

// ---------------------------------------------------------------------------
// K_A: blocks 0..1  : find5 -> seg (pos[0..4], cnt)
//      blocks 2..65 : img16 = (f16)image, imgT16 = transpose, ipart partials
//      blocks 66..67: LayerNorm of real rows -> tn; zero real out rows
// ---------------------------------------------------------------------------
__global__ __launch_bounds__(1024) void kA(
    const int* __restrict__ loc, const float* __restrict__ image,
    const float* __restrict__ text, const float* __restrict__ gamma,
    const float* __restrict__ beta, int* __restrict__ seg,
    float* __restrict__ ipart, _Float16* __restrict__ img16,
    _Float16* __restrict__ imgT16, float* __restrict__ tn,
    float* __restrict__ out) {
  __shared__ _Float16 cvt[32 * 1024];       // 64 KB
  __shared__ int posS[5];
  __shared__ float wred[20];
  const int idx = blockIdx.x;
  const int tid = threadIdx.x;
  if (idx < BATCH) {
    const int b = idx;
    find5(loc, b, posS, tid);
    if (tid == 0) {
#pragma unroll
      for (int k = 0; k < 5; k++) seg[b * 8 + k] = posS[k];
      int cnt = posS[4] - posS[0];
      if (posS[0] >= NTXT) cnt = 0;
      seg[b * 8 + 5] = min(cnt, RMAX);
    }
  } else if (idx < BATCH + 64) {
    // ---- convert + transpose + partial column sums ----
    const int j = idx - BATCH;            // 0..63
    const int b = j >> 5, jt = j & 31;    // 32 row-tiles of 32 per batch
    const int j0 = jt * 32;
    const size_t rbase = (size_t)(b * TM + j0) * DIM + tid;
    float s = 0.f;
#pragma unroll 4
    for (int r = 0; r < 32; r++) {
      const float v = image[rbase + (size_t)r * DIM];
      s += v;
      const _Float16 hv = (_Float16)v;
      img16[rbase + (size_t)r * DIM] = hv;
      cvt[r * 1024 + tid] = hv;
    }
    ipart[(b * 32 + jt) * 1024 + tid] = s;
    __syncthreads();
    // transposed out: thread owns column c = tid
    f16x8 tv[4];
#pragma unroll
    for (int g = 0; g < 4; g++)
#pragma unroll
      for (int u = 0; u < 8; u++)
        tv[g][u] = cvt[(g * 8 + u) * 1024 + tid];
    _Float16* dst = imgT16 + (size_t)(b * DIM + tid) * TM + j0;
#pragma unroll
    for (int g = 0; g < 4; g++)
      *reinterpret_cast<f16x8*>(dst + g * 8) = tv[g];
  } else {
    // ---- LayerNorm of real rows + zero their out rows ----
    const int b = idx - (BATCH + 64);
    find5(loc, b, posS, tid);
    const int pos0 = posS[0];
    int cnt = posS[4] - pos0;
    if (pos0 >= NTXT) cnt = 0;
    cnt = min(cnt, RMAX);
    for (int r = 0; r < cnt; r++) {
      const float x = text[(size_t)(b * NTXT + pos0 + r) * DIM + tid];
      // sum
      float v = x;
#pragma unroll
      for (int off = 32; off; off >>= 1) v += __shfl_xor(v, off, 64);
      if ((tid & 63) == 0) wred[tid >> 6] = v;
      __syncthreads();
      if (tid == 0) {
        float t2 = 0.f;
#pragma unroll
        for (int q = 0; q < 16; q++) t2 += wred[q];
        wred[16] = t2;
      }
      __syncthreads();
      const float mu = wred[16] * (1.0f / DIM);
      __syncthreads();
      // var
      const float d = x - mu;
      float v2 = d * d;
#pragma unroll
      for (int off = 32; off; off >>= 1) v2 += __shfl_xor(v2, off, 64);
      if ((tid & 63) == 0) wred[tid >> 6] = v2;
      __syncthreads();
      if (tid == 0) {
        float t2 = 0.f;
#pragma unroll
        for (int q = 0; q < 16; q++) t2 += wred[q];
        wred[16] = t2;
      }
      __syncthreads();
      const float rstd = rsqrtf(wred[16] * (1.0f / DIM) + 1e-5f);
      __syncthreads();
      tn[(size_t)(b * RMAX + r) * DIM + tid] = d * rstd * gamma[tid] + beta[tid];
      out[(size_t)(b * NTXT + pos0 + r) * DIM + tid] = 0.f;
    }
  }
}

// ---------------------------------------------------------------------------
// K_B: blocks 0..31 : per (b,h): Q = tn @ Wq_h ; U = Q @ Wk_h^T -> U16
//      blocks 32..47: vbar[b,:] = (mean img) @ Wkv_v  (from ipart, no atomics)
// ---------------------------------------------------------------------------
__global__ __launch_bounds__(256) void kB(
    const float* __restrict__ Wq, const float* __restrict__ Wkv,
    const float* __restrict__ tn, const int* __restrict__ seg,
    const float* __restrict__ ipart, _Float16* __restrict__ U16,
    float* __restrict__ vbar) {
  __shared__ float tn_s[8 * 1024];    // 32 KB
  __shared__ float qred[4 * 8 * 64];  // 8 KB
  __shared__ float Qs[8 * 64];        // 2 KB
  __shared__ float wk_s[64 * 65];     // 16.25 KB
  __shared__ float ib_s[1024];
  __shared__ float vred2[256];
  const int idx = blockIdx.x;
  const int tid = threadIdx.x;
  if (idx < 32) {
    const int b = idx >> 4, h = idx & 15;
    const int cnt = seg[b * 8 + 5];
    for (int ic0 = 0; ic0 < cnt; ic0 += 8) {
      const int ni = min(8, cnt - ic0);
      for (int k = tid; k < 8 * 1024; k += 256) {
        const int r = k >> 10;
        tn_s[k] = (r < ni) ? tn[(size_t)(b * RMAX + ic0 + r) * DIM + (k & 1023)]
                           : 0.f;
      }
      __syncthreads();
      {
        const int d = tid & 63, cg = tid >> 6;
        float qp[8] = {};
        for (int c = cg * 256; c < cg * 256 + 256; c++) {
          const float w = Wq[(size_t)c * DIM + h * DHD + d];
#pragma unroll
          for (int i2 = 0; i2 < 8; i2++) qp[i2] += tn_s[i2 * 1024 + c] * w;
        }
#pragma unroll
        for (int i2 = 0; i2 < 8; i2++) qred[(cg * 8 + i2) * 64 + d] = qp[i2];
      }
      __syncthreads();
      for (int k = tid; k < 512; k += 256) {
        const int i2 = k >> 6, d = k & 63;
        Qs[k] = qred[(0 * 8 + i2) * 64 + d] + qred[(1 * 8 + i2) * 64 + d] +
                qred[(2 * 8 + i2) * 64 + d] + qred[(3 * 8 + i2) * 64 + d];
      }
      __syncthreads();
      // U[i][c] = sum_d Q[i][d] * Wkv[c][h*64+d]
      for (int cc = 0; cc < 16; cc++) {
        for (int k = tid; k < 64 * 64; k += 256) {
          const int row = k >> 6, col = k & 63;
          wk_s[row * 65 + col] = Wkv[(size_t)(cc * 64 + row) * KVW + h * DHD + col];
        }
        __syncthreads();
        const int cl = tid & 63, ig = tid >> 6;
#pragma unroll
        for (int ii = 0; ii < 2; ii++) {
          const int i2 = ig * 2 + ii;
          if (i2 < ni) {
            float u = 0.f;
#pragma unroll 8
            for (int d2 = 0; d2 < 64; d2++)
              u += Qs[i2 * 64 + d2] * wk_s[cl * 65 + d2];
            U16[((size_t)b * MCAP + (size_t)(ic0 + i2) * NH + h) * DIM +
                cc * 64 + cl] = (_Float16)u;
          }
        }
        __syncthreads();
      }
    }
  } else {
    // ---- vbar ----
    const int j2 = idx - 32;
    const int b = j2 >> 3, ec = j2 & 7;
    for (int k = tid; k < 1024; k += 256) {
      float s2 = 0.f;
#pragma unroll 4
      for (int p = 0; p < 32; p++) s2 += ipart[(b * 32 + p) * 1024 + k];
      ib_s[k] = s2 * (1.0f / (float)TM);
    }
    __syncthreads();
    const int e = ec * 128 + (tid & 127), half = tid >> 7;
    float s2 = 0.f;
    for (int c = half * 512; c < half * 512 + 512; c++)
      s2 += ib_s[c] * Wkv[(size_t)c * KVW + DIM + e];
    vred2[tid] = s2;
    __syncthreads();
    if (tid < 128)
      vbar[b * DIM + ec * 128 + tid] = vred2[tid] + vred2[128 + tid];
  }
}

// ---------------------------------------------------------------------------
// 128x128 f16 MFMA GEMM tile, K=1024, all strides 1024, f32 output.
// (inner body carried from the round-0/3 verified GEMM)
// ---------------------------------------------------------------------------
__device__ __forceinline__ void gemm128_f32out(
    const _Float16* __restrict__ Abase, const _Float16* __restrict__ Bbase,
    float* __restrict__ Dbase, _Float16* As, _Float16* Bs, int tid) {
  const int lane = tid & 63, wid = tid >> 6;
  const int wm = wid & 3, wn = wid >> 2;
  const int srow = tid >> 3, skc = (tid & 7) * 8;
  const int frow = lane & 15, fq = lane >> 4;
  const int swk = skc ^ ((srow & 7) << 3);
  f32x4 acc[2][4] = {};
  f16x8 a0v = *reinterpret_cast<const f16x8*>(Abase + (size_t)srow * 1024 + skc);
  f16x8 a1v = *reinterpret_cast<const f16x8*>(Abase + (size_t)(srow + 64) * 1024 + skc);
  f16x8 b0v = *reinterpret_cast<const f16x8*>(Bbase + (size_t)srow * 1024 + skc);
  f16x8 b1v = *reinterpret_cast<const f16x8*>(Bbase + (size_t)(srow + 64) * 1024 + skc);
  for (int k0 = 0; k0 < 1024; k0 += 64) {
    __syncthreads();
    *reinterpret_cast<f16x8*>(As + srow * 64 + swk) = a0v;
    *reinterpret_cast<f16x8*>(As + (srow + 64) * 64 + swk) = a1v;
    *reinterpret_cast<f16x8*>(Bs + srow * 64 + swk) = b0v;
    *reinterpret_cast<f16x8*>(Bs + (srow + 64) * 64 + swk) = b1v;
    __syncthreads();
    if (k0 + 64 < 1024) {
      a0v = *reinterpret_cast<const f16x8*>(Abase + (size_t)srow * 1024 + k0 + 64 + skc);
      a1v = *reinterpret_cast<const f16x8*>(Abase + (size_t)(srow + 64) * 1024 + k0 + 64 + skc);
      b0v = *reinterpret_cast<const f16x8*>(Bbase + (size_t)srow * 1024 + k0 + 64 + skc);
      b1v = *reinterpret_cast<const f16x8*>(Bbase + (size_t)(srow + 64) * 1024 + k0 + 64 + skc);
    }
    f16x8 af[2][2], bf[2][4];
#pragma unroll
    for (int kk = 0; kk < 2; kk++) {
#pragma unroll
      for (int mt = 0; mt < 2; mt++) {
        const int r = wm * 32 + mt * 16 + frow;
        af[kk][mt] = *reinterpret_cast<const f16x8*>(
            As + r * 64 + ((kk * 32 + fq * 8) ^ ((r & 7) << 3)));
      }
#pragma unroll
      for (int nt = 0; nt < 4; nt++) {
        const int c = wn * 64 + nt * 16 + frow;
        bf[kk][nt] = *reinterpret_cast<const f16x8*>(
            Bs + c * 64 + ((kk * 32 + fq * 8) ^ ((c & 7) << 3)));
      }
    }
#pragma unroll
    for (int kk = 0; kk < 2; kk++)
#pragma unroll
      for (int mt = 0; mt < 2; mt++)
#pragma unroll
        for (int nt = 0; nt < 4; nt++)
          acc[mt][nt] = __builtin_amdgcn_mfma_f32_16x16x32_f16(
              af[kk][mt], bf[kk][nt], acc[mt][nt], 0, 0, 0);
  }
#pragma unroll
  for (int mt = 0; mt < 2; mt++)
#pragma unroll
    for (int nt = 0; nt < 4; nt++) {
      const int col = wn * 64 + nt * 16 + frow;
#pragma unroll
      for (int r = 0; r < 4; r++) {
        const int row = wm * 32 + mt * 16 + fq * 4 + r;
        Dbase[(size_t)row * 1024 + col] = acc[mt][nt][r];
      }
    }
}

// ---------------------------------------------------------------------------
// K_C: blocks 0..511 : S = U16 @ img16^T   (S[m][j], f32)
//      blocks 512..527: obar = vbar @ Wo
// ---------------------------------------------------------------------------
__global__ __launch_bounds__(512) void kC(
    const _Float16* __restrict__ U16, const _Float16* __restrict__ img16,
    const float* __restrict__ vbar, const float* __restrict__ Wo,
    const int* __restrict__ seg, float* __restrict__ S,
    float* __restrict__ obar) {
  __shared__ __align__(16) char smem[32768];
  __shared__ float vb_s[1024];
  __shared__ float ored[512];
  const int idx = blockIdx.x;
  const int tid = threadIdx.x;
  if (idx < 512) {
    const int b = idx >> 8;
    const int li = idx & 255;
    const int mt = li >> 3, nt = li & 7;
    const int cnt16 = seg[b * 8 + 5] * NH;
    const int row0 = mt * 128;
    if (row0 >= cnt16) return;
    const int col0 = nt * 128;
    _Float16* As = (_Float16*)smem;
    _Float16* Bs = As + 128 * 64;
    gemm128_f32out(U16 + ((size_t)b * MCAP + row0) * DIM,
                   img16 + ((size_t)b * TM + col0) * DIM,
                   S + ((size_t)b * MCAP + row0) * TM + col0, As, Bs, tid);
  } else {
    const int j2 = idx - 512;
    const int b = j2 >> 3, ec = j2 & 7;
    for (int k = tid; k < 1024; k += 512) vb_s[k] = vbar[b * DIM + k];
    __syncthreads();
    const int e = ec * 128 + (tid & 127), qg = tid >> 7;
    float s2 = 0.f;
    for (int c = qg * 256; c < qg * 256 + 256; c++)
      s2 += vb_s[c] * Wo[(size_t)c * DIM + e];
    ored[tid] = s2;
    __syncthreads();
    if (tid < 128)
      obar[b * DIM + ec * 128 + tid] =
          ored[tid] + ored[128 + tid] + ored[256 + tid] + ored[384 + tid];
  }
}

// ---------------------------------------------------------------------------
// K_D: blocks 0..4095   : fill (t=0 -> zero, t>4 -> obar; real rows skipped)
//      blocks 4096..4607: masked softmax: P16[m][:] (zeros outside block t_i)
// ---------------------------------------------------------------------------
__global__ __launch_bounds__(256) void kD(
    const float* __restrict__ S, const int* __restrict__ seg,
    const float* __restrict__ obar, _Float16* __restrict__ P16,
    float* __restrict__ out) {
  __shared__ float wred[4];
  const int idx = blockIdx.x;
  const int tid = threadIdx.x;
  if (idx < BATCH * NTXT) {
    const int b = idx >> 11;
    const int i = idx & (NTXT - 1);
    const int pos0 = seg[b * 8 + 0];
    const int pos4 = seg[b * 8 + 4];
    float* orow = out + (size_t)(b * NTXT + i) * DIM;
    if (i < pos0) {
#pragma unroll
      for (int u = 0; u < 4; u++) orow[tid + 256 * u] = 0.f;
    } else if (i >= pos4) {
      const float* ob = obar + b * DIM;
#pragma unroll
      for (int u = 0; u < 4; u++) orow[tid + 256 * u] = ob[tid + 256 * u];
    }
    // real rows: handled by kA (zero) + kF (atomicAdd)
  } else {
    const int j2 = idx - BATCH * NTXT;    // 0..511
    const int b = j2 >> 8, i = j2 & 255;
    const int cnt = seg[b * 8 + 5];
    if (i >= cnt) return;
    const int pos0 = seg[b * 8 + 0];
    const int ig = pos0 + i;
    const int t = 1 + (ig >= seg[b * 8 + 1]) + (ig >= seg[b * 8 + 2]) +
                  (ig >= seg[b * 8 + 3]);            // in [1,4]
    const int joff = (t - 1) * MMED;
    const int lane = tid & 63, w = tid >> 6;
    for (int h = 0; h < NH; h++) {
      const int m = i * NH + h;
      const float v = S[((size_t)b * MCAP + m) * TM + joff + tid] * 0.125f;
      float mv = v;
#pragma unroll
      for (int off = 32; off; off >>= 1) mv = fmaxf(mv, __shfl_xor(mv, off, 64));
      if (lane == 0) wred[w] = mv;
      __syncthreads();
      mv = fmaxf(fmaxf(wred[0], wred[1]), fmaxf(wred[2], wred[3]));
      const float e = __expf(v - mv);
      float sv = e;
#pragma unroll
      for (int off = 32; off; off >>= 1) sv += __shfl_xor(sv, off, 64);
      __syncthreads();
      if (lane == 0) wred[w] = sv;
      __syncthreads();
      sv = wred[0] + wred[1] + wred[2] + wred[3];
      const float p = e / sv;
      _Float16* prow = P16 + ((size_t)b * MCAP + m) * TM;
#pragma unroll
      for (int u = 0; u < 4; u++)
        prow[tid + 256 * u] = (u == t - 1) ? (_Float16)p : (_Float16)0.f;
      __syncthreads();
    }
  }
}

// ---------------------------------------------------------------------------
// K_E: pbar = P16 @ imgT16^T   (pbar[m][c], f32)
// ---------------------------------------------------------------------------
__global__ __launch_bounds__(512) void kE(
    const _Float16* __restrict__ P16, const _Float16* __restrict__ imgT16,
    const int* __restrict__ seg, float* __restrict__ pbar) {
  __shared__ __align__(16) char smem[32768];
  const int idx = blockIdx.x;
  const int tid = threadIdx.x;
  const int b = idx >> 8;
  const int li = idx & 255;
  const int mt = li >> 3, nt = li & 7;
  const int cnt16 = seg[b * 8 + 5] * NH;
  const int row0 = mt * 128;
  if (row0 >= cnt16) return;
  const int col0 = nt * 128;
  _Float16* As = (_Float16*)smem;
  _Float16* Bs = As + 128 * 64;
  gemm128_f32out(P16 + ((size_t)b * MCAP + row0) * TM,
                 imgT16 + ((size_t)b * DIM + col0) * TM,
                 pbar + ((size_t)b * MCAP + row0) * DIM + col0, As, Bs, tid);
}

// ---------------------------------------------------------------------------
// K_F: per (b,h,ic): av = pbar_row @ Wv_h ; out += av @ Wo_h  (atomicAdd)
// ---------------------------------------------------------------------------
__global__ __launch_bounds__(256) void kF(
    const float* __restrict__ pbar, const float* __restrict__ Wkv,
    const float* __restrict__ Wo, const int* __restrict__ seg,
    float* __restrict__ out) {
  __shared__ float pb_s[1024];
  __shared__ float ared[256];
  __shared__ float av_s[64];
  const int idx = blockIdx.x;
  const int tid = threadIdx.x;
  const int b = idx >> 6, h = (idx >> 2) & 15, ic = idx & 3;
  const int pos0 = seg[b * 8 + 0];
  const int cnt = seg[b * 8 + 5];
  for (int i = ic; i < cnt; i += 4) {
    const int m = i * NH + h;
    for (int k = tid; k < 1024; k += 256)
      pb_s[k] = pbar[((size_t)b * MCAP + m) * DIM + k];
    __syncthreads();
    const int d = tid & 63, cg = tid >> 6;
    float a = 0.f;
    for (int c = cg * 256; c < cg * 256 + 256; c++)
      a += pb_s[c] * Wkv[(size_t)c * KVW + DIM + h * DHD + d];
    ared[cg * 64 + d] = a;
    __syncthreads();
    if (tid < 64)
      av_s[tid] = ared[tid] + ared[64 + tid] + ared[128 + tid] + ared[192 + tid];
    __syncthreads();
    float* orow = out + (size_t)(b * NTXT + pos0 + i) * DIM;
#pragma unroll
    for (int u = 0; u < 4; u++) {
      const int e = tid + 256 * u;
      float o = 0.f;
#pragma unroll 8
      for (int d2 = 0; d2 < 64; d2++)
        o += av_s[d2] * Wo[(size_t)(h * DHD + d2) * DIM + e];
      atomicAdd(&orow[e], o);
    }
    __syncthreads();
  }
}

// ---------------------------------------------------------------------------
extern "C" void kernel_launch(void* const* d_in, const int* in_sizes, int n_in,
                              void* d_out, int out_size, void* d_ws, size_t ws_size,
                              hipStream_t stream) {
  const float* text  = (const float*)d_in[0];
  const float* image = (const float*)d_in[1];
  const int*   loc   = (const int*)d_in[2];
  const float* Wq    = (const float*)d_in[3];
  const float* Wkv   = (const float*)d_in[4];
  const float* Wo    = (const float*)d_in[5];
  const float* gamma = (const float*)d_in[6];
  const float* beta  = (const float*)d_in[7];
  float* out = (float*)d_out;

  // ws layout (~106.5 MB):
  // img16 4MB | imgT16 4MB | U16 16MB | P16 16MB | S 32MB | pbar 32MB |
  // tn 2MB | ipart 0.25MB | vbar | obar | seg
  _Float16* img16  = (_Float16*)d_ws;
  _Float16* imgT16 = img16 + (size_t)BATCH * TM * DIM;
  _Float16* U16    = imgT16 + (size_t)BATCH * DIM * TM;
  _Float16* P16    = U16 + (size_t)BATCH * MCAP * DIM;
  float*    S      = (float*)(P16 + (size_t)BATCH * MCAP * TM);
  float*    pbar   = S + (size_t)BATCH * MCAP * TM;
  float*    tn     = pbar + (size_t)BATCH * MCAP * DIM;
  float*    ipart  = tn + (size_t)BATCH * RMAX * DIM;
  float*    vbar   = ipart + BATCH * 32 * DIM;
  float*    obar   = vbar + BATCH * DIM;
  int*      seg    = (int*)(obar + BATCH * DIM);

  kA<<<BATCH + 64 + BATCH, 1024, 0, stream>>>(loc, image, text, gamma, beta,
                                              seg, ipart, img16, imgT16, tn, out);
  kB<<<48, 256, 0, stream>>>(Wq, Wkv, tn, seg, ipart, U16, vbar);
  kC<<<528, 512, 0, stream>>>(U16, img16, vbar, Wo, seg, S, obar);
  kD<<<BATCH * NTXT + 512, 256, 0, stream>>>(S, seg, obar, P16, out);
  kE<<<512, 512, 0, stream>>>(P16, imgT16, seg, pbar);
  kF<<<128, 256, 0, stream>>>(pbar, Wkv, Wo, seg, out);
}

// Round 5
// 248.645 us; speedup vs baseline: 2.0041x; 2.0041x over previous
//
#include <hip/hip_runtime.h>

// Problem constants (setup_inputs is fixed)
#define BATCH 2
#define NTXT  2048
#define TMED  4
#define MMED  256
#define TM    (TMED * MMED)      // 1024 kv rows per batch
#define DIM   1024
#define NH    16
#define DHD   64
#define KVW   2048               // k|v concatenated width
#define RMAX  256                // max real rows per batch supported

typedef _Float16 f16x8 __attribute__((ext_vector_type(8)));
typedef _Float16 f16x4 __attribute__((ext_vector_type(4)));
typedef float    f32x4 __attribute__((ext_vector_type(4)));

// ---------------------------------------------------------------------------
// find positions of the 1st..5th ones in loc[b,:] (wave 0 only)
// ---------------------------------------------------------------------------
__device__ __forceinline__ void find5(const int* __restrict__ loc, int b,
                                      int* posS, int tid) {
  if (tid < 64) {
    int pos[5] = {NTXT, NTXT, NTXT, NTXT, NTXT};
    int found = 0;
    for (int base = 0; base < NTXT && found < 5; base += 64) {
      unsigned long long m = __ballot(loc[b * NTXT + base + tid] != 0);
      while (m && found < 5) {
        const int p = __ffsll(m) - 1;
        pos[found++] = base + p;
        m &= m - 1;
      }
    }
    if (tid == 0) {
#pragma unroll
      for (int k = 0; k < 5; k++) posS[k] = pos[k];
    }
  }
  __syncthreads();
}

// ---------------------------------------------------------------------------
// K_A: blocks 0..1    : find5 -> seg
//      blocks 2..65   : img16 = (f16)image + ipart column partial sums
//      blocks 66..321 : Wkv k-half (K x 1024 f32) -> WkT16 (1024 x K f16)
//      blocks 322..323: LayerNorm real rows -> tn; zero their out rows
//      blocks 324..339: zero qbuf | av | vbar | obar
// ---------------------------------------------------------------------------
__global__ __launch_bounds__(1024) void kA(
    const int* __restrict__ loc, const float* __restrict__ image,
    const float* __restrict__ text, const float* __restrict__ Wkv,
    const float* __restrict__ gamma, const float* __restrict__ beta,
    int* __restrict__ seg, float* __restrict__ ipart,
    _Float16* __restrict__ img16, _Float16* __restrict__ WkT16,
    float* __restrict__ tn, float* __restrict__ out,
    float* __restrict__ zbase) {
  __shared__ float tile[64][65];
  __shared__ int posS[5];
  __shared__ float wred[20];
  const int idx = blockIdx.x;
  const int tid = threadIdx.x;
  if (idx < BATCH) {
    const int b = idx;
    find5(loc, b, posS, tid);
    if (tid == 0) {
#pragma unroll
      for (int k = 0; k < 5; k++) seg[b * 8 + k] = posS[k];
      int cnt = posS[4] - posS[0];
      if (posS[0] >= NTXT) cnt = 0;
      seg[b * 8 + 5] = min(cnt, RMAX);
    }
  } else if (idx < BATCH + 64) {
    // ---- convert + partial column sums ----
    const int j = idx - BATCH;           // 0..63
    const int b = j >> 5, jt = j & 31;   // 32 row-tiles of 32 per batch
    const size_t rbase = (size_t)(b * TM + jt * 32) * DIM + tid;
    float s = 0.f;
#pragma unroll 4
    for (int r = 0; r < 32; r++) {
      const float v = image[rbase + (size_t)r * DIM];
      s += v;
      img16[rbase + (size_t)r * DIM] = (_Float16)v;
    }
    ipart[(b * 32 + jt) * DIM + tid] = s;
  } else if (idx < BATCH + 64 + 256) {
    // ---- transpose+convert k-half of Wkv ----
    const int j2 = idx - (BATCH + 64);   // 0..255
    const int c0 = (j2 & 15) * 64, n0 = (j2 >> 4) * 64;
    const int r = tid >> 4, c4 = (tid & 15) * 4;
    const float4 v = *reinterpret_cast<const float4*>(
        Wkv + (size_t)(c0 + r) * KVW + n0 + c4);
    tile[r][c4 + 0] = v.x; tile[r][c4 + 1] = v.y;
    tile[r][c4 + 2] = v.z; tile[r][c4 + 3] = v.w;
    __syncthreads();
    if (tid < 512) {
      const int n = tid >> 3, kc = (tid & 7) * 8;
      f16x8 h;
#pragma unroll
      for (int u = 0; u < 8; u++) h[u] = (_Float16)tile[kc + u][n];
      *reinterpret_cast<f16x8*>(WkT16 + (size_t)(n0 + n) * DIM + c0 + kc) = h;
    }
  } else if (idx < BATCH + 64 + 256 + 2) {
    // ---- LayerNorm of real rows + zero their out rows ----
    const int b = idx - (BATCH + 64 + 256);
    find5(loc, b, posS, tid);
    const int pos0 = posS[0];
    int cnt = posS[4] - pos0;
    if (pos0 >= NTXT) cnt = 0;
    cnt = min(cnt, RMAX);
    for (int r = 0; r < cnt; r++) {
      const float x = text[(size_t)(b * NTXT + pos0 + r) * DIM + tid];
      float v = x;
#pragma unroll
      for (int off = 32; off; off >>= 1) v += __shfl_xor(v, off, 64);
      if ((tid & 63) == 0) wred[tid >> 6] = v;
      __syncthreads();
      if (tid == 0) {
        float t2 = 0.f;
#pragma unroll
        for (int q = 0; q < 16; q++) t2 += wred[q];
        wred[16] = t2;
      }
      __syncthreads();
      const float mu = wred[16] * (1.0f / DIM);
      __syncthreads();
      const float d = x - mu;
      float v2 = d * d;
#pragma unroll
      for (int off = 32; off; off >>= 1) v2 += __shfl_xor(v2, off, 64);
      if ((tid & 63) == 0) wred[tid >> 6] = v2;
      __syncthreads();
      if (tid == 0) {
        float t2 = 0.f;
#pragma unroll
        for (int q = 0; q < 16; q++) t2 += wred[q];
        wred[16] = t2;
      }
      __syncthreads();
      const float rstd = rsqrtf(wred[16] * (1.0f / DIM) + 1e-5f);
      __syncthreads();
      tn[(size_t)(b * RMAX + r) * DIM + tid] = d * rstd * gamma[tid] + beta[tid];
      out[(size_t)(b * NTXT + pos0 + r) * DIM + tid] = 0.f;
    }
  } else {
    // ---- zero qbuf(2MB) + av(2MB) + vbar + obar = 263168 float4 ----
    const int j = idx - (BATCH + 64 + 256 + 2);  // 0..15
    float4* z = reinterpret_cast<float4*>(zbase);
    const float4 zv = {0.f, 0.f, 0.f, 0.f};
    for (int i = j * 1024 + tid; i < 263168; i += 16 * 1024) z[i] = zv;
  }
}

// ---------------------------------------------------------------------------
// 64x128 f16 MFMA GEMM tile, K=1024, strides DIM, f16 output.
// ---------------------------------------------------------------------------
__device__ __forceinline__ void gemm64x128_f16(
    const _Float16* __restrict__ A, const _Float16* __restrict__ B,
    _Float16* __restrict__ D, _Float16* As, _Float16* Bs, int tid) {
  const int lane = tid & 63, wid = tid >> 6;
  const int wm = wid & 1, wn = wid >> 1;
  const int srow = tid >> 3, skc = (tid & 7) * 8;
  const int frow = lane & 15, fq = lane >> 4;
  const int swk = skc ^ ((srow & 7) << 3);
  f32x4 acc[2][2] = {};
  f16x8 a0v = *reinterpret_cast<const f16x8*>(A + (size_t)srow * DIM + skc);
  f16x8 b0v = *reinterpret_cast<const f16x8*>(B + (size_t)srow * DIM + skc);
  f16x8 b1v = *reinterpret_cast<const f16x8*>(B + (size_t)(srow + 64) * DIM + skc);
  for (int k0 = 0; k0 < DIM; k0 += 64) {
    __syncthreads();
    *reinterpret_cast<f16x8*>(As + srow * 64 + swk) = a0v;
    *reinterpret_cast<f16x8*>(Bs + srow * 64 + swk) = b0v;
    *reinterpret_cast<f16x8*>(Bs + (srow + 64) * 64 + swk) = b1v;
    __syncthreads();
    if (k0 + 64 < DIM) {
      a0v = *reinterpret_cast<const f16x8*>(A + (size_t)srow * DIM + k0 + 64 + skc);
      b0v = *reinterpret_cast<const f16x8*>(B + (size_t)srow * DIM + k0 + 64 + skc);
      b1v = *reinterpret_cast<const f16x8*>(B + (size_t)(srow + 64) * DIM + k0 + 64 + skc);
    }
    f16x8 af[2][2], bf[2][2];
#pragma unroll
    for (int kk = 0; kk < 2; kk++) {
#pragma unroll
      for (int mt = 0; mt < 2; mt++) {
        const int r = wm * 32 + mt * 16 + frow;
        af[kk][mt] = *reinterpret_cast<const f16x8*>(
            As + r * 64 + ((kk * 32 + fq * 8) ^ ((r & 7) << 3)));
      }
#pragma unroll
      for (int nt = 0; nt < 2; nt++) {
        const int c = wn * 32 + nt * 16 + frow;
        bf[kk][nt] = *reinterpret_cast<const f16x8*>(
            Bs + c * 64 + ((kk * 32 + fq * 8) ^ ((c & 7) << 3)));
      }
    }
#pragma unroll
    for (int kk = 0; kk < 2; kk++)
#pragma unroll
      for (int mt = 0; mt < 2; mt++)
#pragma unroll
        for (int nt = 0; nt < 2; nt++)
          acc[mt][nt] = __builtin_amdgcn_mfma_f32_16x16x32_f16(
              af[kk][mt], bf[kk][nt], acc[mt][nt], 0, 0, 0);
  }
#pragma unroll
  for (int mt = 0; mt < 2; mt++)
#pragma unroll
    for (int nt = 0; nt < 2; nt++) {
      const int col = wn * 32 + nt * 16 + frow;
#pragma unroll
      for (int r = 0; r < 4; r++) {
        const int row = wm * 32 + mt * 16 + fq * 4 + r;
        D[(size_t)row * DIM + col] = (_Float16)acc[mt][nt][r];
      }
    }
}

// ---------------------------------------------------------------------------
// K_B: blocks 0..255  : K16 = img16 @ WkT16^T  (64x128 tiles, MFMA)
//      blocks 256..319: Q skinny GEMM (k-split atomics -> qbuf)
//      blocks 320..351: vbar = (mean img) @ Wkv_v (k-split atomics)
// ---------------------------------------------------------------------------
__global__ __launch_bounds__(512) void kB(
    const _Float16* __restrict__ img16, const _Float16* __restrict__ WkT16,
    const float* __restrict__ Wq, const float* __restrict__ Wkv,
    const float* __restrict__ tn, const int* __restrict__ seg,
    const float* __restrict__ ipart, _Float16* __restrict__ K16,
    float* __restrict__ qbuf, float* __restrict__ vbar) {
  __shared__ __align__(16) char smem[24576];
  const int idx = blockIdx.x;
  const int tid = threadIdx.x;
  if (idx < 256) {
    const int b = idx >> 7, li = idx & 127;
    const int jt = li >> 3, ht = li & 7;
    _Float16* As = (_Float16*)smem;
    _Float16* Bs = As + 64 * 64;
    gemm64x128_f16(img16 + (size_t)(b * TM + jt * 64) * DIM,
                   WkT16 + (size_t)(ht * 128) * DIM,
                   K16 + (size_t)(b * TM + jt * 64) * DIM + ht * 128,
                   As, Bs, tid);
  } else if (idx < 320) {
    // ---- Q: qbuf[r, n0:+128] += tn[r, c0:+256] @ Wq[c0:+256, n0:+128] ----
    float* tn_s = (float*)smem;              // 8 x 256 = 8 KB
    const int j = idx - 256;                 // 0..63
    const int b = j >> 5, nt = (j >> 2) & 7, kc = j & 3;
    const int n0 = nt * 128, c0 = kc * 256;
    const int n = tid & 127, cs = tid >> 7;  // 4 c-quarters of 64
    const int cnt = seg[b * 8 + 5];
    for (int r0 = 0; r0 < cnt; r0 += 8) {
      const int nr = min(8, cnt - r0);
      for (int k = tid; k < 8 * 256; k += 512) {
        const int r = k >> 8, c = k & 255;
        tn_s[k] = (r < nr) ? tn[(size_t)(b * RMAX + r0 + r) * DIM + c0 + c]
                           : 0.f;
      }
      __syncthreads();
      float acc[8] = {};
      for (int ci = 0; ci < 64; ci++) {
        const int c = cs * 64 + ci;
        const float w = Wq[(size_t)(c0 + c) * DIM + n0 + n];
#pragma unroll
        for (int r = 0; r < 8; r++) acc[r] += tn_s[r * 256 + c] * w;
      }
      for (int r = 0; r < nr; r++)
        atomicAdd(&qbuf[(size_t)(b * RMAX + r0 + r) * DIM + n0 + n], acc[r]);
      __syncthreads();
    }
  } else {
    // ---- vbar[b,e] += ibar[c0:+128] @ Wkv[c0:+128, DIM+e] ----
    float* ib_s = (float*)smem;              // 128 f32
    const int j = idx - 320;                 // 0..31
    const int b = j >> 4, sub = j & 15;
    const int kc = sub >> 1, eh = sub & 1;
    const int c0 = kc * 128;
    const int e = eh * 512 + tid;
    if (tid < 128) {
      float s = 0.f;
#pragma unroll 4
      for (int p = 0; p < 32; p++) s += ipart[(b * 32 + p) * DIM + c0 + tid];
      ib_s[tid] = s * (1.0f / (float)TM);
    }
    __syncthreads();
    float s = 0.f;
    for (int ci = 0; ci < 128; ci++)
      s += ib_s[ci] * Wkv[(size_t)(c0 + ci) * KVW + DIM + e];
    atomicAdd(&vbar[b * DIM + e], s);
  }
}

// ---------------------------------------------------------------------------
// K_C: blocks 0..127  : fused scores+softmax+pbar per (b, h, tblock)
//      blocks 128..159: obar = vbar @ Wo (k-split atomics)
// ---------------------------------------------------------------------------
__global__ __launch_bounds__(256) void kC(
    const _Float16* __restrict__ K16, const _Float16* __restrict__ img16,
    const float* __restrict__ qbuf, const float* __restrict__ vbar,
    const float* __restrict__ Wo, const int* __restrict__ seg,
    float* __restrict__ pbar, float* __restrict__ obar) {
  __shared__ float qs[DHD];
  __shared__ float pbuf[256];
  __shared__ float wred[8];
  __shared__ float vb_s[128];
  const int idx = blockIdx.x;
  const int tid = threadIdx.x;
  if (idx < 128) {
    const int b = idx >> 6, h = (idx >> 2) & 15, tb = idx & 3;
    const int p0 = seg[b * 8 + 0], p1 = seg[b * 8 + 1];
    const int p2 = seg[b * 8 + 2], p3 = seg[b * 8 + 3];
    const int cnt = seg[b * 8 + 5];
    const int jg = b * TM + tb * MMED;     // kv-row base of mask block tb
    const int lane = tid & 63, w = tid >> 6;
    for (int i = 0; i < cnt; i++) {
      const int ig = p0 + i;
      const int t = (ig >= p1) + (ig >= p2) + (ig >= p3);  // 0..3
      if (t != tb) continue;
      if (tid < 64) qs[tid] = qbuf[(size_t)(b * RMAX + i) * DIM + h * DHD + tid];
      __syncthreads();
      // score for kv row jg+tid
      const _Float16* kr = K16 + (size_t)(jg + tid) * DIM + h * DHD;
      float s = 0.f;
#pragma unroll
      for (int d8 = 0; d8 < 8; d8++) {
        const f16x8 kk = *reinterpret_cast<const f16x8*>(kr + d8 * 8);
#pragma unroll
        for (int u = 0; u < 8; u++) s += qs[d8 * 8 + u] * (float)kk[u];
      }
      s *= 0.125f;
      // softmax over 256 threads
      float mv = s;
#pragma unroll
      for (int off = 32; off; off >>= 1) mv = fmaxf(mv, __shfl_xor(mv, off, 64));
      if (lane == 0) wred[w] = mv;
      __syncthreads();
      mv = fmaxf(fmaxf(wred[0], wred[1]), fmaxf(wred[2], wred[3]));
      const float e = __expf(s - mv);
      float sv = e;
#pragma unroll
      for (int off = 32; off; off >>= 1) sv += __shfl_xor(sv, off, 64);
      __syncthreads();
      if (lane == 0) wred[4 + w] = sv;
      __syncthreads();
      sv = wred[4] + wred[5] + wred[6] + wred[7];
      pbuf[tid] = e / sv;
      __syncthreads();
      // pbar[i,h,c] = sum_j p[j] * img16[jg+j, c]; thread owns 4 consecutive c
      const int c0 = tid * 4;
      const _Float16* ib = img16 + (size_t)jg * DIM + c0;
      f32x4 acc = {};
      for (int j2 = 0; j2 < 256; j2++) {
        const float pj = pbuf[j2];
        const f16x4 iv = *reinterpret_cast<const f16x4*>(ib + (size_t)j2 * DIM);
        acc[0] += pj * (float)iv[0];
        acc[1] += pj * (float)iv[1];
        acc[2] += pj * (float)iv[2];
        acc[3] += pj * (float)iv[3];
      }
      *reinterpret_cast<f32x4*>(
          pbar + ((size_t)(b * RMAX + i) * NH + h) * DIM + c0) = acc;
      __syncthreads();
    }
  } else {
    // ---- obar ----
    const int j = idx - 128;                 // 0..31
    const int b = j >> 4, sub = j & 15;
    const int kc = sub >> 1, eh = sub & 1;
    const int c0 = kc * 128;
    const int e0 = eh * 512;
    if (tid < 128) vb_s[tid] = vbar[b * DIM + c0 + tid];
    __syncthreads();
    float s0 = 0.f, s1 = 0.f;
    for (int ci = 0; ci < 128; ci++) {
      const float v = vb_s[ci];
      const float* wr = Wo + (size_t)(c0 + ci) * DIM + e0;
      s0 += v * wr[tid];
      s1 += v * wr[tid + 256];
    }
    atomicAdd(&obar[b * DIM + e0 + tid], s0);
    atomicAdd(&obar[b * DIM + e0 + 256 + tid], s1);
  }
}

// ---------------------------------------------------------------------------
// K_D: blocks 0..4095   : fill (t=0 -> zero, t>4 -> obar; real rows skipped)
//      blocks 4096..4223: av[i, h*64+d] += pbar[i,h,c0:+256] @ Wv[c0:+256, hd]
// ---------------------------------------------------------------------------
__global__ __launch_bounds__(256) void kD(
    const int* __restrict__ seg, const float* __restrict__ obar,
    const float* __restrict__ pbar, const float* __restrict__ Wkv,
    float* __restrict__ av, float* __restrict__ out) {
  __shared__ float pb_s[8 * 256];
  __shared__ float ared[256];
  const int idx = blockIdx.x;
  const int tid = threadIdx.x;
  if (idx < BATCH * NTXT) {
    const int b = idx >> 11;
    const int i = idx & (NTXT - 1);
    const int p0 = seg[b * 8 + 0], p4 = seg[b * 8 + 4];
    float4* orow = reinterpret_cast<float4*>(out + (size_t)(b * NTXT + i) * DIM);
    if (i < p0) {
      const float4 zv = {0.f, 0.f, 0.f, 0.f};
      orow[tid] = zv;
    } else if (i >= p4) {
      orow[tid] = reinterpret_cast<const float4*>(obar + b * DIM)[tid];
    }
  } else {
    const int j = idx - BATCH * NTXT;        // 0..127
    const int b = j >> 6, h = (j >> 2) & 15, kc = j & 3;
    const int c0 = kc * 256;
    const int cnt = seg[b * 8 + 5];
    const int d = tid & 63, cg = tid >> 6;   // 4 c-quarters of 64
    for (int r0 = 0; r0 < cnt; r0 += 8) {
      const int nr = min(8, cnt - r0);
      for (int k = tid; k < 8 * 256; k += 256) {
        const int r = k >> 8, c = k & 255;
        pb_s[k] = (r < nr)
            ? pbar[((size_t)(b * RMAX + r0 + r) * NH + h) * DIM + c0 + c]
            : 0.f;
      }
      __syncthreads();
      float acc[8] = {};
      for (int ci = 0; ci < 64; ci++) {
        const float wv =
            Wkv[(size_t)(c0 + cg * 64 + ci) * KVW + DIM + h * DHD + d];
#pragma unroll
        for (int r = 0; r < 8; r++) acc[r] += pb_s[r * 256 + cg * 64 + ci] * wv;
      }
      for (int r = 0; r < nr; r++) {
        ared[tid] = acc[r];
        __syncthreads();
        if (tid < 64)
          atomicAdd(&av[(size_t)(b * RMAX + r0 + r) * DIM + h * DHD + tid],
                    ared[tid] + ared[64 + tid] + ared[128 + tid] + ared[192 + tid]);
        __syncthreads();
      }
      __syncthreads();
    }
  }
}

// ---------------------------------------------------------------------------
// K_E: out[real row i, e0:+256] += av[i, hd0:+64] @ Wo[hd0:+64, e0:+256]
// ---------------------------------------------------------------------------
__global__ __launch_bounds__(256) void kE(
    const int* __restrict__ seg, const float* __restrict__ av,
    const float* __restrict__ Wo, float* __restrict__ out) {
  __shared__ float av_s[8 * 64];
  const int idx = blockIdx.x;
  const int tid = threadIdx.x;
  const int b = idx >> 6, li = idx & 63;
  const int kq = li >> 2, eq = li & 3;
  const int hd0 = kq * 64, e0 = eq * 256;
  const int p0 = seg[b * 8 + 0];
  const int cnt = seg[b * 8 + 5];
  const int e = e0 + tid;
  for (int r0 = 0; r0 < cnt; r0 += 8) {
    const int nr = min(8, cnt - r0);
    for (int k = tid; k < 512; k += 256) {
      const int r = k >> 6, d2 = k & 63;
      av_s[k] = (r < nr) ? av[(size_t)(b * RMAX + r0 + r) * DIM + hd0 + d2]
                         : 0.f;
    }
    __syncthreads();
    float acc[8] = {};
    for (int hd = 0; hd < 64; hd++) {
      const float w = Wo[(size_t)(hd0 + hd) * DIM + e];
#pragma unroll
      for (int r = 0; r < 8; r++) acc[r] += av_s[r * 64 + hd] * w;
    }
    for (int r = 0; r < nr; r++)
      atomicAdd(&out[(size_t)(b * NTXT + p0 + r0 + r) * DIM + e], acc[r]);
    __syncthreads();
  }
}

// ---------------------------------------------------------------------------
extern "C" void kernel_launch(void* const* d_in, const int* in_sizes, int n_in,
                              void* d_out, int out_size, void* d_ws, size_t ws_size,
                              hipStream_t stream) {
  const float* text  = (const float*)d_in[0];
  const float* image = (const float*)d_in[1];
  const int*   loc   = (const int*)d_in[2];
  const float* Wq    = (const float*)d_in[3];
  const float* Wkv   = (const float*)d_in[4];
  const float* Wo    = (const float*)d_in[5];
  const float* gamma = (const float*)d_in[6];
  const float* beta  = (const float*)d_in[7];
  float* out = (float*)d_out;

  // ws layout (~48.3 MB):
  // img16 4MB | WkT16 2MB | K16 4MB | tn 2MB | pbar 32MB | ipart 256KB |
  // [zeroed in kA: qbuf 2MB | av 2MB | vbar | obar] | seg
  _Float16* img16 = (_Float16*)d_ws;
  _Float16* WkT16 = img16 + (size_t)BATCH * TM * DIM;
  _Float16* K16   = WkT16 + (size_t)DIM * DIM;
  float*    tn    = (float*)(K16 + (size_t)BATCH * TM * DIM);
  float*    pbar  = tn + (size_t)BATCH * RMAX * DIM;
  float*    ipart = pbar + (size_t)BATCH * RMAX * NH * DIM;
  float*    qbuf  = ipart + BATCH * 32 * DIM;
  float*    av    = qbuf + (size_t)BATCH * RMAX * DIM;
  float*    vbar  = av + (size_t)BATCH * RMAX * DIM;
  float*    obar  = vbar + BATCH * DIM;
  int*      seg   = (int*)(obar + BATCH * DIM);

  kA<<<BATCH + 64 + 256 + 2 + 16, 1024, 0, stream>>>(
      loc, image, text, Wkv, gamma, beta, seg, ipart, img16, WkT16, tn, out, qbuf);
  kB<<<352, 512, 0, stream>>>(img16, WkT16, Wq, Wkv, tn, seg, ipart,
                              K16, qbuf, vbar);
  kC<<<160, 256, 0, stream>>>(K16, img16, qbuf, vbar, Wo, seg, pbar, obar);
  kD<<<BATCH * NTXT + 128, 256, 0, stream>>>(seg, obar, pbar, Wkv, av, out);
  kE<<<128, 256, 0, stream>>>(seg, av, Wo, out);
}

// Round 6
// 152.665 us; speedup vs baseline: 3.2640x; 1.6287x over previous
//
#include <hip/hip_runtime.h>

// Problem constants (setup_inputs is fixed)
#define BATCH 2
#define NTXT  2048
#define TMED  4
#define MMED  256
#define TM    (TMED * MMED)      // 1024 kv rows per batch
#define DIM   1024
#define NH    16
#define DHD   64
#define KVW   2048               // k|v concatenated width
#define RMAX  256                // max real rows per batch handled by fast path
#define RT    32                 // row-tile parallelism for heavy-path kernels

typedef _Float16 f16x8 __attribute__((ext_vector_type(8)));
typedef float    f32x4 __attribute__((ext_vector_type(4)));

// ---------------------------------------------------------------------------
// K1: blocks 0..1   : inclusive scan of locations -> txt_time + segment
//     blocks 2..257 : ipart column partial sums of image (no img16 anymore)
//     blocks 258..769: Wkv (K x N f32) -> WkvT (N x K f16) transpose
//     blocks 770..785: zero qbuf|vbar|obar
// ---------------------------------------------------------------------------
__global__ __launch_bounds__(1024) void k1_scan_cvt_tr(
    const int* __restrict__ loc, const float* __restrict__ image,
    const float* __restrict__ Wkv, int* __restrict__ tt, int* __restrict__ seg,
    float* __restrict__ ipart, _Float16* __restrict__ WkvT,
    float* __restrict__ zbase) {
  __shared__ float tile[64][65];
  __shared__ int wtot[16];
  __shared__ int wmin[2][16];
  const int idx = blockIdx.x;
  const int tid = threadIdx.x;
  if (idx < BATCH) {
    // ---- scan: each thread owns 2 consecutive elements ----
    const int b = idx;
    const int lane = tid & 63, w = tid >> 6;
    const int e0 = tid * 2;
    const int a0 = loc[b * NTXT + e0], a1 = loc[b * NTXT + e0 + 1];
    const int p = a0 + a1;
    int incl = p;
#pragma unroll
    for (int off = 1; off < 64; off <<= 1) {
      const int t2 = __shfl_up(incl, off, 64);
      if (lane >= off) incl += t2;
    }
    if (lane == 63) wtot[w] = incl;
    __syncthreads();
    if (tid < 16) {
      const int v = wtot[tid];
      int inc2 = v;
#pragma unroll
      for (int off = 1; off < 16; off <<= 1) {
        const int t3 = __shfl_up(inc2, off, 64);
        if (tid >= off) inc2 += t3;
      }
      wtot[tid] = inc2 - v;          // exclusive prefix for wave tid
    }
    __syncthreads();
    const int base = wtot[w] + (incl - p);
    const int t0v = base + a0, t1v = t0v + a1;
    tt[b * NTXT + e0]     = t0v;
    tt[b * NTXT + e0 + 1] = t1v;
    {
      const int c1 = (t1v >= 1) ? ((t0v >= 1) ? e0 : e0 + 1) : NTXT;
      const int c5 = (t1v >= 5) ? ((t0v >= 5) ? e0 : e0 + 1) : NTXT;
      const unsigned long long b1 = __ballot(t1v >= 1);
      const unsigned long long b5 = __ballot(t1v >= 5);
      int m1 = NTXT, m5 = NTXT;
      if (b1) m1 = __shfl(c1, __ffsll(b1) - 1, 64);
      if (b5) m5 = __shfl(c5, __ffsll(b5) - 1, 64);
      if (lane == 0) { wmin[0][w] = m1; wmin[1][w] = m5; }
    }
    __syncthreads();
    if (tid == 0) {
      int s = NTXT, e = NTXT;
#pragma unroll
      for (int i = 0; i < 16; i++) {
        s = min(s, wmin[0][i]);
        e = min(e, wmin[1][i]);
      }
      seg[b * 2]     = s;
      seg[b * 2 + 1] = e - s;
    }
  } else if (idx < BATCH + 256) {
    // ---- image partial column sums (conversion now fused into k3 GEMM) ----
    const int j = idx - BATCH;           // 0..255
    const int b = j >> 7, rt = j & 127;  // 128 row-tiles of 8 per batch
    const size_t base = (size_t)(b * TM + rt * 8) * DIM + tid;
    const float* p = image + base;
    float s = 0.f;
#pragma unroll
    for (int r = 0; r < 8; r++) s += p[(size_t)r * DIM];
    ipart[(size_t)(b * 128 + rt) * DIM + tid] = s;
  } else if (idx < BATCH + 256 + 512) {
    // ---- transpose+convert Wkv (64x64 tiles, 1024 threads) ----
    const int j2 = idx - BATCH - 256;    // 0..511
    const int k0 = (j2 & 15) * 64, n0 = (j2 >> 4) * 64;
    const int r = tid >> 4, c4 = (tid & 15) * 4;
    const float4 v = *reinterpret_cast<const float4*>(
        Wkv + (size_t)(k0 + r) * KVW + n0 + c4);
    tile[r][c4 + 0] = v.x; tile[r][c4 + 1] = v.y;
    tile[r][c4 + 2] = v.z; tile[r][c4 + 3] = v.w;
    __syncthreads();
    if (tid < 512) {
      const int n = tid >> 3, kc = (tid & 7) * 8;
      f16x8 h;
#pragma unroll
      for (int u = 0; u < 8; u++) h[u] = (_Float16)tile[kc + u][n];
      *reinterpret_cast<f16x8*>(WkvT + (size_t)(n0 + n) * DIM + k0 + kc) = h;
    }
  } else {
    // ---- zero qbuf + vbar + obar (528384 floats = 132096 float4) ----
    const int j = idx - (BATCH + 256 + 512);   // 0..15
    float4* z = reinterpret_cast<float4*>(zbase);
    const float4 zv = {0.f, 0.f, 0.f, 0.f};
    for (int i = j * 1024 + tid; i < 132096; i += 16 * 1024) z[i] = zv;
  }
}

// ---------------------------------------------------------------------------
// K2: blocks 0..63  : LayerNorm of real rows -> tn
//     blocks 64..127: vbar[b,e] += (reduce ipart -> ibar chunk) @ Wkv_v
//     blocks 128..129: zero real-segment out rows (k4 attnh atomicAdds there)
// ---------------------------------------------------------------------------
__global__ __launch_bounds__(256) void k2_prep(
    const float* __restrict__ Wkv, const float* __restrict__ text,
    const float* __restrict__ gamma, const float* __restrict__ beta,
    const int* __restrict__ seg, const float* __restrict__ ipart,
    float* __restrict__ tn, float* __restrict__ vbar,
    float* __restrict__ out) {
  __shared__ float red[256];
  const int idx = blockIdx.x;
  const int tid = threadIdx.x;
  if (idx < 64) {
    // ---- LayerNorm of real rows ----
    const int b = idx >> 5, rt = idx & 31;
    const int i0 = seg[b * 2];
    const int cnt = min(seg[b * 2 + 1], RMAX);
    for (int r = rt; r < cnt; r += RT) {
      const float* xrow = text + (size_t)(b * NTXT + i0 + r) * DIM;
      float x[4];
      float s = 0.f;
#pragma unroll
      for (int u = 0; u < 4; u++) { x[u] = xrow[tid + 256 * u]; s += x[u]; }
      red[tid] = s; __syncthreads();
      for (int st = 128; st > 0; st >>= 1) {
        if (tid < st) red[tid] += red[tid + st];
        __syncthreads();
      }
      const float mu = red[0] * (1.0f / DIM); __syncthreads();
      float vs = 0.f;
#pragma unroll
      for (int u = 0; u < 4; u++) { float d = x[u] - mu; vs += d * d; }
      red[tid] = vs; __syncthreads();
      for (int st = 128; st > 0; st >>= 1) {
        if (tid < st) red[tid] += red[tid + st];
        __syncthreads();
      }
      const float rstd = rsqrtf(red[0] * (1.0f / DIM) + 1e-5f); __syncthreads();
      float* trow = tn + (size_t)(b * RMAX + r) * DIM;
#pragma unroll
      for (int u = 0; u < 4; u++) {
        const int c = tid + 256 * u;
        trow[c] = (x[u] - mu) * rstd * gamma[c] + beta[c];
      }
      __syncthreads();
    }
  } else if (idx < 128) {
    // ---- vbar partial matvec (c-chunked) ----
    const int j = idx - 64;             // 0..63
    const int b = j >> 5, et = (j >> 3) & 3, cc = j & 7;
    const int e = et * 256 + tid;
    const int c0 = cc * 128;
    if (tid < 128) {
      float s = 0.f;
      for (int p = 0; p < 128; p++)
        s += ipart[(size_t)(b * 128 + p) * DIM + c0 + tid];
      red[tid] = s * (1.0f / (float)TM);
    }
    __syncthreads();
    float s = 0.f;
    for (int c = 0; c < 128; c++)
      s += red[c] * Wkv[(size_t)(c0 + c) * KVW + DIM + e];
    atomicAdd(&vbar[b * DIM + e], s);
  } else {
    // ---- zero real-segment output rows ----
    const int b = idx - 128;
    const int i0 = seg[b * 2];
    const int cnt = min(seg[b * 2 + 1], RMAX);
    for (int r = 0; r < cnt; r++) {
      float* orow = out + (size_t)(b * NTXT + i0 + r) * DIM;
      for (int c = tid; c < DIM; c += 256) orow[c] = 0.f;
    }
  }
}

// ---------------------------------------------------------------------------
// K3: blocks 0..255  : f16 MFMA GEMM kv16 = (f16)image @ WkvT^T
//                      (round-0 128x128/BK=32/8-wave body; A staged directly
//                       from f32 image with on-the-fly convert -> kv16
//                       bit-identical; XCD-bijective block swizzle for L2)
//     blocks 256..319: qproj partials (c-chunked, r-inner FMA, atomics)
//     blocks 320..351: obar partials  (c-chunked, atomics)
// ---------------------------------------------------------------------------
__global__ __launch_bounds__(512) void k3_gemm_qproj_obar(
    const float* __restrict__ image, const _Float16* __restrict__ WkvT,
    const float* __restrict__ Wq, const float* __restrict__ Wo,
    const float* __restrict__ tn, const float* __restrict__ vbar,
    const int* __restrict__ seg, _Float16* __restrict__ kv16,
    float* __restrict__ qbuf, float* __restrict__ obar) {
  __shared__ __align__(16) char smem[16384];
  const int idx = blockIdx.x;
  const int tid = threadIdx.x;
  if (idx < 256) {
    // ---- GEMM ----
    _Float16* As = (_Float16*)smem;          // 128*32 f16 = 8 KB
    _Float16* Bs = As + 128 * 32;            // 8 KB
    // XCD-bijective swizzle: XCD (idx%8) owns row-panels 2x..2x+1 ->
    // its 1MB A-slice and the 4MB WkvT become L2-resident.
    const int swz = (idx & 7) * 32 + (idx >> 3);
    const int lane = tid & 63, wid = tid >> 6;
    const int wm = wid & 3, wn = wid >> 2;
    const int row0 = (swz >> 4) * 128, col0 = (swz & 15) * 128;
    const int srow = tid >> 2, skc = (tid & 3) * 8;
    const int frow = lane & 15, fq = lane >> 4;
    const float*    aptr = image + (size_t)(row0 + srow) * DIM + skc;
    const _Float16* bptr = WkvT + (size_t)(col0 + srow) * DIM + skc;
    f32x4 acc[2][4] = {};
    for (int k0 = 0; k0 < DIM; k0 += 32) {
      const float4 av0 = *reinterpret_cast<const float4*>(aptr + k0);
      const float4 av1 = *reinterpret_cast<const float4*>(aptr + k0 + 4);
      const f16x8 bv = *reinterpret_cast<const f16x8*>(bptr + k0);
      f16x8 ah;
      ah[0] = (_Float16)av0.x; ah[1] = (_Float16)av0.y;
      ah[2] = (_Float16)av0.z; ah[3] = (_Float16)av0.w;
      ah[4] = (_Float16)av1.x; ah[5] = (_Float16)av1.y;
      ah[6] = (_Float16)av1.z; ah[7] = (_Float16)av1.w;
      __syncthreads();
      *reinterpret_cast<f16x8*>(As + tid * 8) = ah;
      *reinterpret_cast<f16x8*>(Bs + tid * 8) = bv;
      __syncthreads();
      f16x8 af[2], bf[4];
#pragma unroll
      for (int mt = 0; mt < 2; mt++)
        af[mt] = *reinterpret_cast<const f16x8*>(
            As + (wm * 32 + mt * 16 + frow) * 32 + fq * 8);
#pragma unroll
      for (int nt = 0; nt < 4; nt++)
        bf[nt] = *reinterpret_cast<const f16x8*>(
            Bs + (wn * 64 + nt * 16 + frow) * 32 + fq * 8);
#pragma unroll
      for (int mt = 0; mt < 2; mt++)
#pragma unroll
        for (int nt = 0; nt < 4; nt++)
          acc[mt][nt] = __builtin_amdgcn_mfma_f32_16x16x32_f16(
              af[mt], bf[nt], acc[mt][nt], 0, 0, 0);
    }
#pragma unroll
    for (int mt = 0; mt < 2; mt++)
#pragma unroll
      for (int nt = 0; nt < 4; nt++) {
        const int col = col0 + wn * 64 + nt * 16 + frow;
#pragma unroll
        for (int r = 0; r < 4; r++) {
          const int row = row0 + wm * 32 + mt * 16 + fq * 4 + r;
          kv16[(size_t)row * KVW + col] = (_Float16)acc[mt][nt][r];
        }
      }
  } else if (idx < 320) {
    // ---- qproj: q[r, n0:n0+128] += tn[r, c0:c0+256] @ Wq[c0:c0+256, n] ----
    float* tn_s = (float*)smem;              // 8 rows x 256 c = 8 KB
    const int j = idx - 256;                 // 0..63
    const int b = j >> 5, nt = (j >> 2) & 7, cc = j & 3;
    const int n0 = nt * 128, c0 = cc * 256;
    const int n = tid & 127, cs = tid >> 7;  // 4 c-subchunks of 64
    const int cnt = min(seg[b * 2 + 1], RMAX);
    for (int r0 = 0; r0 < cnt; r0 += 8) {
      const int rows = min(8, cnt - r0);
      for (int i = tid; i < 8 * 256; i += 512) {
        const int r = i >> 8, c = i & 255;
        tn_s[i] = (r < rows) ? tn[(size_t)(b * RMAX + r0 + r) * DIM + c0 + c]
                             : 0.f;
      }
      __syncthreads();
      float acc[8] = {};
      for (int ci = 0; ci < 64; ci++) {
        const int c = cs * 64 + ci;
        const float w = Wq[(size_t)(c0 + c) * DIM + n0 + n];
#pragma unroll
        for (int rr = 0; rr < 8; rr++) acc[rr] += tn_s[rr * 256 + c] * w;
      }
      for (int rr = 0; rr < rows; rr++)
        atomicAdd(&qbuf[(size_t)(b * RMAX + r0 + rr) * DIM + n0 + n], acc[rr]);
      __syncthreads();
    }
  } else {
    // ---- obar: obar[b,e] += vbar[b, c0:c0+128] @ Wo[c0:c0+128, e] ----
    float* vb_s = (float*)smem;              // 128 f32
    const int j = idx - 320;                 // 0..31
    const int b = j >> 4, et = (j >> 3) & 1, cc = j & 7;
    const int e = et * 512 + tid;
    const int c0 = cc * 128;
    if (tid < 128) vb_s[tid] = vbar[b * DIM + c0 + tid];
    __syncthreads();
    float s = 0.f;
    for (int c = 0; c < 128; c++)
      s += vb_s[c] * Wo[(size_t)(c0 + c) * DIM + e];
    atomicAdd(&obar[b * DIM + e], s);
  }
}

// ---------------------------------------------------------------------------
// K4: blocks 0..4095    : fill (zero / obar / fallback), float4 stores
//     blocks 4096..5119 : attnh (q from qbuf, scores, softmax, PV,
//                         fused per-head oproj -> atomicAdd into out)
// ---------------------------------------------------------------------------
__global__ __launch_bounds__(256) void k4_fill_attn(
    const float* __restrict__ text, const _Float16* __restrict__ kv16,
    const float* __restrict__ Wq, const float* __restrict__ Wo,
    const float* __restrict__ gamma, const float* __restrict__ beta,
    const int* __restrict__ tt, const int* __restrict__ seg,
    const float* __restrict__ obar, const float* __restrict__ qbuf,
    float* __restrict__ out) {
  __shared__ float red[256];
  __shared__ float pbuf[256];
  const int idx = blockIdx.x;
  const int tid = threadIdx.x;
  if (idx < BATCH * NTXT) {
    const int b = idx >> 11;
    const int i = idx & (NTXT - 1);
    const int t = tt[b * NTXT + i];
    float* orow = out + (size_t)(b * NTXT + i) * DIM;
    if (t == 0) {
      const float4 zv = {0.f, 0.f, 0.f, 0.f};
      reinterpret_cast<float4*>(orow)[tid] = zv;
      return;
    }
    if (t > TMED) {
      reinterpret_cast<float4*>(orow)[tid] =
          reinterpret_cast<const float4*>(obar + b * DIM)[tid];
      return;
    }
    if (i - seg[b * 2] < RMAX) return;
    // ---- slow fallback (unreachable for realistic data) ----
    __shared__ float tns[DIM];
    __shared__ float qrow[DIM];
    __shared__ float oaccs[DIM];
    const float* xrow = text + (size_t)(b * NTXT + i) * DIM;
    float x[4];
    float s = 0.f;
#pragma unroll
    for (int u = 0; u < 4; u++) { x[u] = xrow[tid + 256 * u]; s += x[u]; }
    red[tid] = s; __syncthreads();
    for (int st = 128; st > 0; st >>= 1) {
      if (tid < st) red[tid] += red[tid + st];
      __syncthreads();
    }
    const float mu = red[0] * (1.0f / DIM); __syncthreads();
    float vs = 0.f;
#pragma unroll
    for (int u = 0; u < 4; u++) { float d = x[u] - mu; vs += d * d; }
    red[tid] = vs; __syncthreads();
    for (int st = 128; st > 0; st >>= 1) {
      if (tid < st) red[tid] += red[tid + st];
      __syncthreads();
    }
    const float rstd = rsqrtf(red[0] * (1.0f / DIM) + 1e-5f); __syncthreads();
#pragma unroll
    for (int u = 0; u < 4; u++) {
      const int c = tid + 256 * u;
      tns[c] = (x[u] - mu) * rstd * gamma[c] + beta[c];
    }
    __syncthreads();
    {
      float qa[4] = {0.f, 0.f, 0.f, 0.f};
      for (int c = 0; c < DIM; c++) {
        const float tv = tns[c];
        const float* w = Wq + (size_t)c * DIM + tid;
#pragma unroll
        for (int u = 0; u < 4; u++) qa[u] += tv * w[256 * u];
      }
#pragma unroll
      for (int u = 0; u < 4; u++) qrow[tid + 256 * u] = qa[u];
    }
    __syncthreads();
    const size_t kvrow0 = (size_t)(b * TM + (t - 1) * MMED) * KVW;
    const int d0 = tid & 63, g = tid >> 6;
    for (int h = 0; h < NH; h++) {
      const _Float16* krow = kv16 + kvrow0 + (size_t)tid * KVW + h * DHD;
      float sc = 0.f;
#pragma unroll
      for (int d = 0; d < DHD; d++) sc += qrow[h * DHD + d] * (float)krow[d];
      sc *= 0.125f;
      red[tid] = sc; __syncthreads();
      for (int st = 128; st > 0; st >>= 1) {
        if (tid < st) red[tid] = fmaxf(red[tid], red[tid + st]);
        __syncthreads();
      }
      const float mx = red[0]; __syncthreads();
      const float e = __expf(sc - mx);
      red[tid] = e; __syncthreads();
      for (int st = 128; st > 0; st >>= 1) {
        if (tid < st) red[tid] += red[tid + st];
        __syncthreads();
      }
      const float inv = 1.0f / red[0]; __syncthreads();
      pbuf[tid] = e * inv; __syncthreads();
      const _Float16* vbase = kv16 + kvrow0 + (size_t)(g * 64) * KVW + DIM + h * DHD + d0;
      float a = 0.f;
#pragma unroll 8
      for (int jj = 0; jj < 64; jj++) a += pbuf[g * 64 + jj] * (float)vbase[(size_t)jj * KVW];
      red[tid] = a; __syncthreads();
      if (tid < 64)
        oaccs[h * DHD + tid] = red[tid] + red[64 + tid] + red[128 + tid] + red[192 + tid];
      __syncthreads();
    }
    float oa[4] = {0.f, 0.f, 0.f, 0.f};
    for (int c = 0; c < DIM; c++) {
      const float ov = oaccs[c];
      const float* w = Wo + (size_t)c * DIM + tid;
#pragma unroll
      for (int u = 0; u < 4; u++) oa[u] += ov * w[256 * u];
    }
#pragma unroll
    for (int u = 0; u < 4; u++) orow[tid + 256 * u] = oa[u];
  } else {
    // ---- attnh with fused per-head output projection ----
    __shared__ float qs[DHD];
    __shared__ float osl[DHD];
    const int j = idx - BATCH * NTXT;       // 0..1023
    const int h = j & 15, rt = (j >> 4) & 31, b = j >> 9;
    const int i0 = seg[b * 2];
    const int cnt = min(seg[b * 2 + 1], RMAX);
    const int d0 = tid & 63, g = tid >> 6;
    for (int r = rt; r < cnt; r += RT) {
      const int i = i0 + r;
      const int t = tt[b * NTXT + i];       // in [1, TMED]
      if (tid < 64) qs[tid] = qbuf[(size_t)(b * RMAX + r) * DIM + h * DHD + tid];
      __syncthreads();
      const size_t kvrow0 = (size_t)(b * TM + (t - 1) * MMED) * KVW;
      const _Float16* krow = kv16 + kvrow0 + (size_t)tid * KVW + h * DHD;
      float sc = 0.f;
#pragma unroll
      for (int d = 0; d < DHD; d += 8) {
        const f16x8 kk = *reinterpret_cast<const f16x8*>(krow + d);
#pragma unroll
        for (int u = 0; u < 8; u++) sc += qs[d + u] * (float)kk[u];
      }
      sc *= 0.125f;
      red[tid] = sc; __syncthreads();
      for (int st = 128; st > 0; st >>= 1) {
        if (tid < st) red[tid] = fmaxf(red[tid], red[tid + st]);
        __syncthreads();
      }
      const float mx = red[0]; __syncthreads();
      const float e = __expf(sc - mx);
      red[tid] = e; __syncthreads();
      for (int st = 128; st > 0; st >>= 1) {
        if (tid < st) red[tid] += red[tid + st];
        __syncthreads();
      }
      const float inv = 1.0f / red[0]; __syncthreads();
      pbuf[tid] = e * inv; __syncthreads();
      const _Float16* vbase = kv16 + kvrow0 + (size_t)(g * 64) * KVW + DIM + h * DHD + d0;
      float a = 0.f;
#pragma unroll 8
      for (int jj = 0; jj < 64; jj++) a += pbuf[g * 64 + jj] * (float)vbase[(size_t)jj * KVW];
      red[tid] = a; __syncthreads();
      if (tid < 64)
        osl[tid] = red[tid] + red[64 + tid] + red[128 + tid] + red[192 + tid];
      __syncthreads();
      // fused partial oproj: out[i,:] += osl @ Wo[h*64 : h*64+64, :]
      float* orow = out + (size_t)(b * NTXT + i) * DIM;
#pragma unroll
      for (int u = 0; u < 4; u++) {
        const int c = tid + 256 * u;
        const float* w = Wo + (size_t)(h * DHD) * DIM + c;
        float s2 = 0.f;
#pragma unroll 8
        for (int d = 0; d < DHD; d++) s2 += osl[d] * w[(size_t)d * DIM];
        atomicAdd(&orow[c], s2);
      }
      __syncthreads();
    }
  }
}

// ---------------------------------------------------------------------------
extern "C" void kernel_launch(void* const* d_in, const int* in_sizes, int n_in,
                              void* d_out, int out_size, void* d_ws, size_t ws_size,
                              hipStream_t stream) {
  const float* text  = (const float*)d_in[0];
  const float* image = (const float*)d_in[1];
  const int*   loc   = (const int*)d_in[2];
  const float* Wq    = (const float*)d_in[3];
  const float* Wkv   = (const float*)d_in[4];
  const float* Wo    = (const float*)d_in[5];
  const float* gamma = (const float*)d_in[6];
  const float* beta  = (const float*)d_in[7];
  float* out = (float*)d_out;

  // ws layout: kv16 8MB | WkvT 4MB | tn 2MB |
  //            [k1-zeroed: qbuf 2MB | vbar | obar] | tt | seg | ipart 1MB
  _Float16* kv16  = (_Float16*)d_ws;
  _Float16* WkvT  = kv16 + (size_t)BATCH * TM * KVW;
  float*    tn    = (float*)(WkvT + (size_t)KVW * DIM);
  float*    qbuf  = tn + (size_t)BATCH * RMAX * DIM;
  float*    vbar  = qbuf + (size_t)BATCH * RMAX * DIM;
  float*    obar  = vbar + BATCH * DIM;
  int*      tt    = (int*)(obar + BATCH * DIM);
  int*      seg   = tt + BATCH * NTXT;
  float*    ipart = (float*)(seg + 8);                 // 256*1024 f32 = 1MB

  k1_scan_cvt_tr<<<BATCH + 256 + 512 + 16, 1024, 0, stream>>>(
      loc, image, Wkv, tt, seg, ipart, WkvT, qbuf);
  k2_prep<<<130, 256, 0, stream>>>(Wkv, text, gamma, beta, seg, ipart,
                                   tn, vbar, out);
  k3_gemm_qproj_obar<<<352, 512, 0, stream>>>(image, WkvT, Wq, Wo, tn, vbar,
                                              seg, kv16, qbuf, obar);
  k4_fill_attn<<<BATCH * NTXT + NH * RT * BATCH, 256, 0, stream>>>(
      text, kv16, Wq, Wo, gamma, beta, tt, seg, obar, qbuf, out);
}